// Round 20
// baseline (167.305 us; speedup 1.0000x reference)
//
#include <hip/hip_runtime.h>

typedef unsigned short u16;
typedef __attribute__((ext_vector_type(8))) short s8v;           // bf16x8 MFMA frag
typedef __attribute__((ext_vector_type(8))) unsigned short us8;  // 16B copy vector
typedef __attribute__((ext_vector_type(4))) float f4v;           // MFMA acc frag
typedef __attribute__((ext_vector_type(2))) float fp2;           // packed f32 pair

#define L2E 1.4426950408889634f

typedef __attribute__((address_space(1))) void gvoid_t;
typedef __attribute__((address_space(3))) void lvoid_t;

__device__ __forceinline__ u16 f2bf(float f) {
  unsigned u = __builtin_bit_cast(unsigned, f);
  return (u16)((u + 0x7FFFu + ((u >> 16) & 1u)) >> 16);
}
__device__ __forceinline__ float bf2f(u16 h) {
  return __builtin_bit_cast(float, ((unsigned)h) << 16);
}
__device__ __forceinline__ f4v mfma16(s8v a, s8v b, f4v c) {
  return __builtin_amdgcn_mfma_f32_16x16x32_bf16(a, b, c, 0, 0, 0);
}
__device__ __forceinline__ float exp2fast(float x) {
#if __has_builtin(__builtin_amdgcn_exp2f)
  return __builtin_amdgcn_exp2f(x);
#else
  return exp2f(x);
#endif
}
// async global->LDS, 16B per lane; LDS dest = uniform base + lane*16
__device__ __forceinline__ void stage16(const u16* g, u16* lds_arr, int slot) {
#if __has_builtin(__builtin_amdgcn_global_load_lds)
  __builtin_amdgcn_global_load_lds((gvoid_t*)(g),
      (lvoid_t*)(lds_arr + (size_t)(slot & ~63) * 8), 16, 0, 0);
#else
  *(us8*)(lds_arr + (size_t)slot * 8) = *(const us8*)g;
#endif
}

// ---------------- merged prep: x->bf16 | W_heads^T | W_out^T ----------------
__global__ __launch_bounds__(256) void prep_all(const float* __restrict__ x,
                                                u16* __restrict__ xb,
                                                const float* __restrict__ Wh,
                                                u16* __restrict__ Wta,
                                                const float* __restrict__ Wo,
                                                u16* __restrict__ Wto) {
  int bid = blockIdx.x;
  if (bid < 2048) {
    int i = (bid * 256 + threadIdx.x) * 8;
    float4 v0 = *(const float4*)(x + i);
    float4 v1 = *(const float4*)(x + i + 4);
    us8 o;
    o[0] = f2bf(v0.x); o[1] = f2bf(v0.y); o[2] = f2bf(v0.z); o[3] = f2bf(v0.w);
    o[4] = f2bf(v1.x); o[5] = f2bf(v1.y); o[6] = f2bf(v1.z); o[7] = f2bf(v1.w);
    *(us8*)(xb + i) = o;
  } else if (bid < 3072) {
    int idx = (bid - 2048) * 256 + threadIdx.x;  // h*65536 + k*128 + f
    int h = idx >> 16, k = (idx >> 7) & 511, f = idx & 127;
    Wta[(size_t)(h * 128 + f) * 512 + k] = f2bf(Wh[idx]);
  } else {
    int idx = (bid - 3072) * 256 + threadIdx.x;  // k*256 + c
    int k = idx >> 8, c = idx & 255;
    Wto[(size_t)c * 512 + k] = f2bf(Wo[idx]);
  }
}

// adj int32 [4][2048][2048] -> bitmask [4*2048][64 words]
__global__ __launch_bounds__(256) void prep_adj(const int* __restrict__ adj,
                                                unsigned* __restrict__ adjw) {
  int chunk = blockIdx.x * 4 + (threadIdx.x >> 6);
  int l = threadIdx.x & 63;
  int v = adj[(size_t)chunk * 64 + l];
  unsigned long long m = __ballot(v != 0);
  if (l == 0) {
    ((uint2*)adjw)[chunk] = make_uint2((unsigned)m, (unsigned)(m >> 32));
  }
}

// ---------------- GEMM: C^T = (A[M,512] @ B) stored as Ct[b][col][n] bf16 ----
// 64x64 tiles, BK=32 dbuf, T2 XOR swizzle (R13 verified).
__global__ __launch_bounds__(256) void gemm_bf16(const u16* __restrict__ A,
                                                 const u16* __restrict__ Bt,
                                                 u16* __restrict__ Ct, int CO) {
  const int K = 512, N = 2048;
  int m0 = blockIdx.x * 64;
  int n0 = blockIdx.y * 64;
  int t = threadIdx.x;
  int w = t >> 6, l = t & 63, lr = l & 15, lq = l >> 4;
  int wr = w >> 1, wc = w & 1;
  __shared__ u16 As[2][64 * 32];
  __shared__ u16 Bs[2][64 * 32];
  f4v zero4 = {0.f, 0.f, 0.f, 0.f};
  f4v acc[2][2];
#pragma unroll
  for (int i = 0; i < 2; ++i)
#pragma unroll
    for (int j = 0; j < 2; ++j) acc[i][j] = zero4;

  auto stage = [&](int buf, int kt) {
    int k0 = kt * 32;
    int row = t >> 2, ch = t & 3;
    int q = (ch ^ ((row >> 1) & 3)) * 8;
    stage16(A + (size_t)(m0 + row) * K + k0 + q, As[buf], t);
    stage16(Bt + (size_t)(n0 + row) * K + k0 + q, Bs[buf], t);
  };
  stage(0, 0);
  int swz = (lq ^ ((lr >> 1) & 3)) * 8;
  for (int kt = 0; kt < 16; ++kt) {
    __syncthreads();
    if (kt < 15) stage((kt + 1) & 1, kt + 1);
    const u16* as = As[kt & 1];
    const u16* bs = Bs[kt & 1];
    s8v af[2], bfr[2];
#pragma unroll
    for (int rf = 0; rf < 2; ++rf)
      af[rf] = *(const s8v*)&as[(wr * 32 + rf * 16 + lr) * 32 + swz];
#pragma unroll
    for (int nf = 0; nf < 2; ++nf)
      bfr[nf] = *(const s8v*)&bs[(wc * 32 + nf * 16 + lr) * 32 + swz];
#pragma unroll
    for (int rf = 0; rf < 2; ++rf)
#pragma unroll
      for (int nf = 0; nf < 2; ++nf)
        acc[rf][nf] = mfma16(af[rf], bfr[nf], acc[rf][nf]);
  }
  int bidx = m0 >> 11;
  int nr0 = m0 & 2047;
#pragma unroll
  for (int rf = 0; rf < 2; ++rf) {
#pragma unroll
    for (int nf = 0; nf < 2; ++nf) {
      int col = n0 + wc * 32 + nf * 16 + lr;
      int nr = nr0 + wr * 32 + rf * 16 + lq * 4;
      f4v a = acc[rf][nf];
      ushort4 v = make_ushort4(f2bf(a[0]), f2bf(a[1]), f2bf(a[2]), f2bf(a[3]));
      *(ushort4*)&Ct[((size_t)bidx * CO + col) * N + nr] = v;
    }
  }
}

// ---------------- f1/f2 (scaled by log2e) from Wh_t ----------------
__global__ __launch_bounds__(256) void fkern(const u16* __restrict__ Wht,
                                             const float* __restrict__ a,
                                             float* __restrict__ f1L,
                                             float* __restrict__ f2L, int COLS,
                                             int F) {
  const int N = 2048;
  int h = blockIdx.z, b = blockIdx.y;
  int nl = threadIdx.x & 63, fc = threadIdx.x >> 6;
  int n = blockIdx.x * 64 + nl;
  int F4 = F >> 2;
  const u16* colp = Wht + ((size_t)(b * COLS + h * F + fc * F4)) * N + n;
  const float* ah = a + h * 2 * F + fc * F4;
  float a1 = 0.f, a2 = 0.f;
  for (int c = 0; c < F4; ++c) {
    float v = bf2f(colp[(size_t)c * N]);
    a1 = fmaf(v, ah[c], a1);
    a2 = fmaf(v, ah[F + c], a2);
  }
  __shared__ float r1[4][64], r2[4][64];
  r1[fc][nl] = a1;
  r2[fc][nl] = a2;
  __syncthreads();
  if (fc == 0) {
    float s1 = r1[0][nl] + r1[1][nl] + r1[2][nl] + r1[3][nl];
    float s2 = r2[0][nl] + r2[1][nl] + r2[2][nl] + r2[3][nl];
    f1L[(size_t)(h * 4 + b) * N + n] = s1 * L2E;
    f2L[(size_t)(h * 4 + b) * N + n] = s2 * L2E;
  }
}

// max over N of f2 per (h,b) row; optionally zeroes pool
__global__ __launch_bounds__(256) void fmax_kern(const float* __restrict__ f2L,
                                                 float* __restrict__ f2m,
                                                 float* __restrict__ pool) {
  int row = blockIdx.x;
  const float* p = f2L + (size_t)row * 2048;
  int t = threadIdx.x;
  if (pool) pool[row * 256 + t] = 0.f;
  float v = -__builtin_inff();
  for (int k = 0; k < 8; ++k) v = fmaxf(v, p[t + k * 256]);
#pragma unroll
  for (int d = 1; d < 64; d <<= 1) v = fmaxf(v, __shfl_xor(v, d));
  __shared__ float wm[4];
  if ((t & 63) == 0) wm[t >> 6] = v;
  __syncthreads();
  if (t == 0) f2m[row] = fmaxf(fmaxf(wm[0], wm[1]), fmaxf(wm[2], wm[3]));
}

// ---------------- fused GAT attention, fixed-max softmax ----------------
// R18 core (factored scores, V dbuf + T2 swizzle, ones-MFMA row sums),
// generalized to NW waves: block = (b, 128-col panel, ROWS=WR*16 rows),
// NW waves = WR row-strips x WC col-slices. attn1 uses NW=8/WR=8 (ROWS=128):
// halves LDS frag-read + stage-write volume per unit work vs ROWS=64.
template <int CT, int NW, int WR, bool ELU>
__global__ __launch_bounds__(NW * 64, 2) void attn_kernel(
    const u16* __restrict__ Wht, const float* __restrict__ f1L,
    const float* __restrict__ f2L, const float* __restrict__ f2max,
    const unsigned* __restrict__ adjw, const float* __restrict__ mask,
    void* __restrict__ outp, float* __restrict__ pool) {
  const int N = 2048;
  constexpr int TPB = NW * 64;
  constexpr int WC = NW / WR;      // col-slice waves
  constexpr int NF = 8 / WC;       // col frags per wave
  constexpr int NCH = CT / 128;    // 128-col panels
  constexpr int ROWS = WR * 16;
  constexpr int NT = 2048 / ROWS;
  constexpr int SJ = 1024 / TPB;   // stage iterations (1024 slots)
  constexpr int FHD = (CT == 512) ? 1 : 0;
  // XCD-aware decode: panel p pinned to XCD p&7
  int kb = blockIdx.x;
  int x = kb & 7, g = kb >> 3;
  int p = x + 8 * (g / NT);
  int it = g % NT;
  int b = p / NCH, ch = p % NCH;
  int i0 = it * ROWS, col0 = ch * 128;
  int fh = FHD ? ch : 0;  // f-arrays per 128-col head (L2: single head 0)
  int t = threadIdx.x;
  int w = t >> 6, l = t & 63, lr = l & 15, lq = l >> 4;
  int wc = w & (WC - 1), wrs = w / WC;

  __shared__ u16 Vs[2][128 * 64];       // 32 KB dbuf, XOR-swizzled
  __shared__ unsigned adjs[ROWS * 65];  // padded bit-words
  __shared__ float e2s[2048];           // exp2(f2j)
  __shared__ float e2n[2048];           // exp2(0.2*f2j)

  const float* f1p = f1L + (size_t)(fh * 4 + b) * N + i0;
  const float* f2p = f2L + (size_t)(fh * 4 + b) * N;
  float f2m = f2max[fh * 4 + b];
  float f1v = f1p[wrs * 16 + lr];
  float su = f1v + f2m;
  float M = fmaxf(su, 0.2f * su);  // fixed per-row max bound
  float c1 = f1v - M;
  float c2 = 0.2f * f1v - M;
  float A = exp2fast(c1);
  float Bv = exp2fast(c2);
  fp2 Ap = {A, A}, Bp = {Bv, Bv};
  const u16* vbase = Wht + (size_t)(b * CT + col0) * 2048;

  // prologue: stage adj words + factored exp tables into LDS, stage V tile 0
  for (int i = t; i < ROWS * 64; i += TPB) {
    int row = i >> 6, wd = i & 63;
    adjs[row * 65 + wd] = adjw[(size_t)(b * N + i0 + row) * 64 + wd];
  }
  for (int i = t; i < 2048; i += TPB) {
    float v = f2p[i];
    e2s[i] = exp2fast(v);
    e2n[i] = exp2fast(0.2f * v);
  }

  auto stage = [&](int buf, int kt) {
    int k0 = kt * 64;
#pragma unroll
    for (int j2 = 0; j2 < SJ; ++j2) {
      int s = j2 * TPB + t;
      int c = s >> 3, q = s & 7;
      // T2: linear LDS dest + inverse-swizzled global source chunk
      stage16(vbase + (size_t)c * 2048 + k0 + (q ^ (c & 7)) * 8, Vs[buf], s);
    }
  };
  stage(0, 0);

  f4v zero4 = {0.f, 0.f, 0.f, 0.f};
  f4v acc[NF], accs = zero4;
#pragma unroll
  for (int j = 0; j < NF; ++j) acc[j] = zero4;
  s8v ones;
#pragma unroll
  for (int i = 0; i < 8; ++i) ones[i] = (short)0x3F80;  // bf16 1.0

  for (int kt = 0; kt < 32; ++kt) {
    __syncthreads();
    if (kt < 31) stage((kt + 1) & 1, kt + 1);
    const u16* vs = Vs[kt & 1];
#pragma unroll
    for (int kk = 0; kk < 2; ++kk) {
      int jt = kt * 2 + kk;
      s8v vf[NF];
#pragma unroll
      for (int nf = 0; nf < NF; ++nf) {
        int c = wc * (NF * 16) + nf * 16 + lr;    // (c&7) == (lr&7)
        int chn = (kk * 4 + lq) ^ (lr & 7);       // same XOR on read
        vf[nf] = *(const s8v*)&vs[c * 64 + chn * 8];
      }
      float4 pa4 = *(const float4*)&e2s[jt * 32 + lq * 8];
      float4 pb4 = *(const float4*)&e2s[jt * 32 + lq * 8 + 4];
      float4 na4 = *(const float4*)&e2n[jt * 32 + lq * 8];
      float4 nb4 = *(const float4*)&e2n[jt * 32 + lq * 8 + 4];
      float ps[8] = {pa4.x, pa4.y, pa4.z, pa4.w, pb4.x, pb4.y, pb4.z, pb4.w};
      float ns[8] = {na4.x, na4.y, na4.z, na4.w, nb4.x, nb4.y, nb4.z, nb4.w};
      unsigned awl = adjs[(wrs * 16 + lr) * 65 + jt] >> (lq * 8);
      union { s8v v; unsigned u[4]; } pk;
#pragma unroll
      for (int ep = 0; ep < 4; ++ep) {
        fp2 ep2 = {ps[2 * ep], ps[2 * ep + 1]};
        fp2 en2 = {ns[2 * ep], ns[2 * ep + 1]};
        fp2 pm = __builtin_elementwise_max(Ap * ep2, Bp * en2);
        float p0 = ((awl >> (2 * ep)) & 1u) ? pm[0] : 0.f;
        float p1 = ((awl >> (2 * ep + 1)) & 1u) ? pm[1] : 0.f;
        asm("v_cvt_pk_bf16_f32 %0, %1, %2"
            : "=v"(pk.u[ep]) : "v"(p0), "v"(p1));
      }
      s8v pa = pk.v;
      accs = mfma16(pa, ones, accs);  // row sums in C/D layout
#pragma unroll
      for (int nf = 0; nf < NF; ++nf)
        acc[nf] = mfma16(pa, vf[nf], acc[nf]);
    }
  }
  // accs[r] = full row sum for output row lq*4+r (all k covered by MFMA)
  f4v i4;
#pragma unroll
  for (int r = 0; r < 4; ++r) i4[r] = 1.f / fmaxf(accs[r], 1e-30f);
  int rowb = i0 + wrs * 16 + lq * 4;
  if constexpr (ELU) {
#pragma unroll
    for (int nf = 0; nf < NF; ++nf) {
      int col = col0 + wc * (NF * 16) + nf * 16 + lr;
#pragma unroll
      for (int r = 0; r < 4; ++r) {
        float v = acc[nf][r] * i4[r];
        v = v > 0.f ? v : exp2fast(v * L2E) - 1.f;
        ((u16*)outp)[(size_t)(b * N + rowb + r) * CT + col] = f2bf(v);
      }
    }
  } else {
    float mk[4];
#pragma unroll
    for (int r = 0; r < 4; ++r) mk[r] = mask[b * N + rowb + r];
#pragma unroll
    for (int nf = 0; nf < NF; ++nf) {
      int col = col0 + wc * (NF * 16) + nf * 16 + lr;
      float cs = 0.f;
#pragma unroll
      for (int r = 0; r < 4; ++r) {
        float vm = acc[nf][r] * i4[r] * mk[r];
        ((float*)outp)[(size_t)(b * N + rowb + r) * CT + col] = vm;
        cs += vm;
      }
      // fused pool1: column partial sums (sum over this wave's 16 rows)
      cs += __shfl_xor(cs, 16);
      cs += __shfl_xor(cs, 32);
      if (l < 16) atomicAdd(&pool[b * 256 + col], cs);
    }
  }
}

// ---------------- pooling epilogue: den from mask + final GEMM --------------
__global__ __launch_bounds__(256) void pool2(const float* __restrict__ pool,
                                             const float* __restrict__ mask,
                                             const float* __restrict__ Wp,
                                             const float* __restrict__ bp,
                                             float* __restrict__ out) {
  int b = blockIdx.x, f = threadIdx.x;
  __shared__ float pv[256];
  __shared__ float ds[256];
  float m = 0.f;
#pragma unroll
  for (int k = 0; k < 8; ++k) m += mask[b * 2048 + f + k * 256];
  ds[f] = m;
  __syncthreads();
  for (int s = 128; s > 0; s >>= 1) {
    if (f < s) ds[f] += ds[f + s];
    __syncthreads();
  }
  float inv = 1.f / (ds[0] + 1e-10f);
  pv[f] = pool[b * 256 + f] * inv;
  __syncthreads();
  float acc = bp[f];
  for (int c = 0; c < 256; ++c) acc = fmaf(pv[c], Wp[c * 256 + f], acc);
  out[b * 256 + f] = fmaxf(acc, 0.f);
}

// ---------------- launcher ----------------
extern "C" void kernel_launch(void* const* d_in, const int* in_sizes, int n_in,
                              void* d_out, int out_size, void* d_ws,
                              size_t ws_size, hipStream_t stream) {
  (void)in_sizes; (void)n_in; (void)out_size; (void)ws_size;
  const float* x = (const float*)d_in[0];
  const int* adj = (const int*)d_in[1];
  const float* mask = (const float*)d_in[2];
  const float* Whds = (const float*)d_in[3];
  const float* ahds = (const float*)d_in[4];
  const float* Wout = (const float*)d_in[5];
  const float* aout = (const float*)d_in[6];
  const float* Wpool = (const float*)d_in[7];
  const float* bpool = (const float*)d_in[8];
  float* out = (float*)d_out;

  char* ws = (char*)d_ws;
  size_t off = 0;
  auto take = [&](size_t n) {
    char* p = ws + off;
    off += (n + 255) & ~(size_t)255;
    return p;
  };
  u16* xb = (u16*)take(8192ull * 512 * 2);
  u16* Wta = (u16*)take(512ull * 512 * 2);
  u16* Wto = (u16*)take(256ull * 512 * 2);
  unsigned* adjw = (unsigned*)take(4ull * 2048 * 64 * 4);
  u16* Wht = (u16*)take(4ull * 512 * 2048 * 2);
  float* f1a = (float*)take(4ull * 4 * 2048 * 4);
  float* f2a = (float*)take(4ull * 4 * 2048 * 4);
  u16* xcat = (u16*)take(8192ull * 512 * 2);
  u16* Wh2t = (u16*)take(4ull * 256 * 2048 * 2);
  float* f1b = (float*)take(4ull * 2048 * 4);
  float* f2b = (float*)take(4ull * 2048 * 4);
  float* f2ma = (float*)take(16 * 4);
  float* f2mb = (float*)take(4 * 4);
  float* pool = (float*)take(1024 * 4);

  prep_all<<<3584, 256, 0, stream>>>(x, xb, Whds, Wta, Wout, Wto);
  prep_adj<<<65536, 256, 0, stream>>>(adj, adjw);
  gemm_bf16<<<dim3(128, 8), 256, 0, stream>>>(xb, Wta, Wht, 512);
  fkern<<<dim3(32, 4, 4), 256, 0, stream>>>(Wht, ahds, f1a, f2a, 512, 128);
  fmax_kern<<<16, 256, 0, stream>>>(f2a, f2ma, nullptr);
  attn_kernel<512, 8, 8, true><<<256, 512, 0, stream>>>(
      Wht, f1a, f2a, f2ma, adjw, nullptr, xcat, nullptr);
  gemm_bf16<<<dim3(128, 4), 256, 0, stream>>>(xcat, Wto, Wh2t, 256);
  fkern<<<dim3(32, 4, 1), 256, 0, stream>>>(Wh2t, aout, f1b, f2b, 256, 256);
  fmax_kern<<<4, 256, 0, stream>>>(f2b, f2mb, pool);
  attn_kernel<256, 4, 2, false><<<512, 256, 0, stream>>>(
      Wh2t, f1b, f2b, f2mb, adjw, mask, out + 1024, pool);
  pool2<<<4, 256, 0, stream>>>(pool, mask, Wpool, bpool, out);
}

// Round 21
// 163.567 us; speedup vs baseline: 1.0229x; 1.0229x over previous
//
#include <hip/hip_runtime.h>

typedef unsigned short u16;
typedef __attribute__((ext_vector_type(8))) short s8v;           // bf16x8 MFMA frag
typedef __attribute__((ext_vector_type(8))) unsigned short us8;  // 16B copy vector
typedef __attribute__((ext_vector_type(4))) float f4v;           // MFMA acc frag
typedef __attribute__((ext_vector_type(2))) float fp2;           // packed f32 pair

#define L2E 1.4426950408889634f

typedef __attribute__((address_space(1))) void gvoid_t;
typedef __attribute__((address_space(3))) void lvoid_t;

__device__ __forceinline__ u16 f2bf(float f) {
  unsigned u = __builtin_bit_cast(unsigned, f);
  return (u16)((u + 0x7FFFu + ((u >> 16) & 1u)) >> 16);
}
__device__ __forceinline__ float bf2f(u16 h) {
  return __builtin_bit_cast(float, ((unsigned)h) << 16);
}
__device__ __forceinline__ f4v mfma16(s8v a, s8v b, f4v c) {
  return __builtin_amdgcn_mfma_f32_16x16x32_bf16(a, b, c, 0, 0, 0);
}
__device__ __forceinline__ float exp2fast(float x) {
#if __has_builtin(__builtin_amdgcn_exp2f)
  return __builtin_amdgcn_exp2f(x);
#else
  return exp2f(x);
#endif
}
// async global->LDS, 16B per lane; LDS dest = uniform base + lane*16
__device__ __forceinline__ void stage16(const u16* g, u16* lds_arr, int slot) {
#if __has_builtin(__builtin_amdgcn_global_load_lds)
  __builtin_amdgcn_global_load_lds((gvoid_t*)(g),
      (lvoid_t*)(lds_arr + (size_t)(slot & ~63) * 8), 16, 0, 0);
#else
  *(us8*)(lds_arr + (size_t)slot * 8) = *(const us8*)g;
#endif
}

// ---------------- merged prep: x->bf16 | W_heads^T | W_out^T ----------------
__global__ __launch_bounds__(256) void prep_all(const float* __restrict__ x,
                                                u16* __restrict__ xb,
                                                const float* __restrict__ Wh,
                                                u16* __restrict__ Wta,
                                                const float* __restrict__ Wo,
                                                u16* __restrict__ Wto) {
  int bid = blockIdx.x;
  if (bid < 2048) {
    int i = (bid * 256 + threadIdx.x) * 8;
    float4 v0 = *(const float4*)(x + i);
    float4 v1 = *(const float4*)(x + i + 4);
    us8 o;
    o[0] = f2bf(v0.x); o[1] = f2bf(v0.y); o[2] = f2bf(v0.z); o[3] = f2bf(v0.w);
    o[4] = f2bf(v1.x); o[5] = f2bf(v1.y); o[6] = f2bf(v1.z); o[7] = f2bf(v1.w);
    *(us8*)(xb + i) = o;
  } else if (bid < 3072) {
    int idx = (bid - 2048) * 256 + threadIdx.x;  // h*65536 + k*128 + f
    int h = idx >> 16, k = (idx >> 7) & 511, f = idx & 127;
    Wta[(size_t)(h * 128 + f) * 512 + k] = f2bf(Wh[idx]);
  } else {
    int idx = (bid - 3072) * 256 + threadIdx.x;  // k*256 + c
    int k = idx >> 8, c = idx & 255;
    Wto[(size_t)c * 512 + k] = f2bf(Wo[idx]);
  }
}

// adj int32 [4][2048][2048] -> bitmask [4*2048][64 words]
__global__ __launch_bounds__(256) void prep_adj(const int* __restrict__ adj,
                                                unsigned* __restrict__ adjw) {
  int chunk = blockIdx.x * 4 + (threadIdx.x >> 6);
  int l = threadIdx.x & 63;
  int v = adj[(size_t)chunk * 64 + l];
  unsigned long long m = __ballot(v != 0);
  if (l == 0) {
    ((uint2*)adjw)[chunk] = make_uint2((unsigned)m, (unsigned)(m >> 32));
  }
}

// ---------------- GEMM: C^T = (A[M,512] @ B) stored as Ct[b][col][n] bf16 ----
// 64x64 tiles, BK=32 dbuf, T2 XOR swizzle (R13 verified).
__global__ __launch_bounds__(256) void gemm_bf16(const u16* __restrict__ A,
                                                 const u16* __restrict__ Bt,
                                                 u16* __restrict__ Ct, int CO) {
  const int K = 512, N = 2048;
  int m0 = blockIdx.x * 64;
  int n0 = blockIdx.y * 64;
  int t = threadIdx.x;
  int w = t >> 6, l = t & 63, lr = l & 15, lq = l >> 4;
  int wr = w >> 1, wc = w & 1;
  __shared__ u16 As[2][64 * 32];
  __shared__ u16 Bs[2][64 * 32];
  f4v zero4 = {0.f, 0.f, 0.f, 0.f};
  f4v acc[2][2];
#pragma unroll
  for (int i = 0; i < 2; ++i)
#pragma unroll
    for (int j = 0; j < 2; ++j) acc[i][j] = zero4;

  auto stage = [&](int buf, int kt) {
    int k0 = kt * 32;
    int row = t >> 2, ch = t & 3;
    int q = (ch ^ ((row >> 1) & 3)) * 8;
    stage16(A + (size_t)(m0 + row) * K + k0 + q, As[buf], t);
    stage16(Bt + (size_t)(n0 + row) * K + k0 + q, Bs[buf], t);
  };
  stage(0, 0);
  int swz = (lq ^ ((lr >> 1) & 3)) * 8;
  for (int kt = 0; kt < 16; ++kt) {
    __syncthreads();
    if (kt < 15) stage((kt + 1) & 1, kt + 1);
    const u16* as = As[kt & 1];
    const u16* bs = Bs[kt & 1];
    s8v af[2], bfr[2];
#pragma unroll
    for (int rf = 0; rf < 2; ++rf)
      af[rf] = *(const s8v*)&as[(wr * 32 + rf * 16 + lr) * 32 + swz];
#pragma unroll
    for (int nf = 0; nf < 2; ++nf)
      bfr[nf] = *(const s8v*)&bs[(wc * 32 + nf * 16 + lr) * 32 + swz];
#pragma unroll
    for (int rf = 0; rf < 2; ++rf)
#pragma unroll
      for (int nf = 0; nf < 2; ++nf)
        acc[rf][nf] = mfma16(af[rf], bfr[nf], acc[rf][nf]);
  }
  int bidx = m0 >> 11;
  int nr0 = m0 & 2047;
#pragma unroll
  for (int rf = 0; rf < 2; ++rf) {
#pragma unroll
    for (int nf = 0; nf < 2; ++nf) {
      int col = n0 + wc * 32 + nf * 16 + lr;
      int nr = nr0 + wr * 32 + rf * 16 + lq * 4;
      f4v a = acc[rf][nf];
      ushort4 v = make_ushort4(f2bf(a[0]), f2bf(a[1]), f2bf(a[2]), f2bf(a[3]));
      *(ushort4*)&Ct[((size_t)bidx * CO + col) * N + nr] = v;
    }
  }
}

// ---------------- f1/f2 (scaled by log2e) from Wh_t ----------------
__global__ __launch_bounds__(256) void fkern(const u16* __restrict__ Wht,
                                             const float* __restrict__ a,
                                             float* __restrict__ f1L,
                                             float* __restrict__ f2L, int COLS,
                                             int F) {
  const int N = 2048;
  int h = blockIdx.z, b = blockIdx.y;
  int nl = threadIdx.x & 63, fc = threadIdx.x >> 6;
  int n = blockIdx.x * 64 + nl;
  int F4 = F >> 2;
  const u16* colp = Wht + ((size_t)(b * COLS + h * F + fc * F4)) * N + n;
  const float* ah = a + h * 2 * F + fc * F4;
  float a1 = 0.f, a2 = 0.f;
  for (int c = 0; c < F4; ++c) {
    float v = bf2f(colp[(size_t)c * N]);
    a1 = fmaf(v, ah[c], a1);
    a2 = fmaf(v, ah[F + c], a2);
  }
  __shared__ float r1[4][64], r2[4][64];
  r1[fc][nl] = a1;
  r2[fc][nl] = a2;
  __syncthreads();
  if (fc == 0) {
    float s1 = r1[0][nl] + r1[1][nl] + r1[2][nl] + r1[3][nl];
    float s2 = r2[0][nl] + r2[1][nl] + r2[2][nl] + r2[3][nl];
    f1L[(size_t)(h * 4 + b) * N + n] = s1 * L2E;
    f2L[(size_t)(h * 4 + b) * N + n] = s2 * L2E;
  }
}

// max over N of f2 per (h,b) row; optionally zeroes pool
__global__ __launch_bounds__(256) void fmax_kern(const float* __restrict__ f2L,
                                                 float* __restrict__ f2m,
                                                 float* __restrict__ pool) {
  int row = blockIdx.x;
  const float* p = f2L + (size_t)row * 2048;
  int t = threadIdx.x;
  if (pool) pool[row * 256 + t] = 0.f;
  float v = -__builtin_inff();
  for (int k = 0; k < 8; ++k) v = fmaxf(v, p[t + k * 256]);
#pragma unroll
  for (int d = 1; d < 64; d <<= 1) v = fmaxf(v, __shfl_xor(v, d));
  __shared__ float wm[4];
  if ((t & 63) == 0) wm[t >> 6] = v;
  __syncthreads();
  if (t == 0) f2m[row] = fmaxf(fmaxf(wm[0], wm[1]), fmaxf(wm[2], wm[3]));
}

// ---------------- fused GAT attention, fixed-max softmax ----------------
// R19 verified best: factored scores p = max(A*E2[j], B*E2n[j]) with
// per-block exp tables in LDS (no per-element transcendentals); V dbuf
// staging via global_load_lds with T2 XOR swizzle; adj bit-words in LDS;
// ones-MFMA row sums; fused pool1 column sums for !ELU.
template <int CT, int NW, int WR, bool ELU>
__global__ __launch_bounds__(NW * 64, 2) void attn_kernel(
    const u16* __restrict__ Wht, const float* __restrict__ f1L,
    const float* __restrict__ f2L, const float* __restrict__ f2max,
    const unsigned* __restrict__ adjw, const float* __restrict__ mask,
    void* __restrict__ outp, float* __restrict__ pool) {
  const int N = 2048;
  constexpr int TPB = NW * 64;
  constexpr int WC = NW / WR;      // col-slice waves
  constexpr int NF = 8 / WC;       // col frags per wave
  constexpr int NCH = CT / 128;    // 128-col panels
  constexpr int ROWS = WR * 16;
  constexpr int NT = 2048 / ROWS;
  constexpr int SJ = 1024 / TPB;   // stage iterations (1024 slots)
  constexpr int FHD = (CT == 512) ? 1 : 0;
  // XCD-aware decode: panel p pinned to XCD p&7
  int kb = blockIdx.x;
  int x = kb & 7, g = kb >> 3;
  int p = x + 8 * (g / NT);
  int it = g % NT;
  int b = p / NCH, ch = p % NCH;
  int i0 = it * ROWS, col0 = ch * 128;
  int fh = FHD ? ch : 0;  // f-arrays per 128-col head (L2: single head 0)
  int t = threadIdx.x;
  int w = t >> 6, l = t & 63, lr = l & 15, lq = l >> 4;
  int wc = w & (WC - 1), wrs = w / WC;

  __shared__ u16 Vs[2][128 * 64];       // 32 KB dbuf, XOR-swizzled
  __shared__ unsigned adjs[ROWS * 65];  // padded bit-words
  __shared__ float e2s[2048];           // exp2(f2j)
  __shared__ float e2n[2048];           // exp2(0.2*f2j)

  const float* f1p = f1L + (size_t)(fh * 4 + b) * N + i0;
  const float* f2p = f2L + (size_t)(fh * 4 + b) * N;
  float f2m = f2max[fh * 4 + b];
  float f1v = f1p[wrs * 16 + lr];
  float su = f1v + f2m;
  float M = fmaxf(su, 0.2f * su);  // fixed per-row max bound
  float c1 = f1v - M;
  float c2 = 0.2f * f1v - M;
  float A = exp2fast(c1);
  float Bv = exp2fast(c2);
  fp2 Ap = {A, A}, Bp = {Bv, Bv};
  const u16* vbase = Wht + (size_t)(b * CT + col0) * 2048;

  // prologue: stage adj words + factored exp tables into LDS, stage V tile 0
  for (int i = t; i < ROWS * 64; i += TPB) {
    int row = i >> 6, wd = i & 63;
    adjs[row * 65 + wd] = adjw[(size_t)(b * N + i0 + row) * 64 + wd];
  }
  for (int i = t; i < 2048; i += TPB) {
    float v = f2p[i];
    e2s[i] = exp2fast(v);
    e2n[i] = exp2fast(0.2f * v);
  }

  auto stage = [&](int buf, int kt) {
    int k0 = kt * 64;
#pragma unroll
    for (int j2 = 0; j2 < SJ; ++j2) {
      int s = j2 * TPB + t;
      int c = s >> 3, q = s & 7;
      // T2: linear LDS dest + inverse-swizzled global source chunk
      stage16(vbase + (size_t)c * 2048 + k0 + (q ^ (c & 7)) * 8, Vs[buf], s);
    }
  };
  stage(0, 0);

  f4v zero4 = {0.f, 0.f, 0.f, 0.f};
  f4v acc[NF], accs = zero4;
#pragma unroll
  for (int j = 0; j < NF; ++j) acc[j] = zero4;
  s8v ones;
#pragma unroll
  for (int i = 0; i < 8; ++i) ones[i] = (short)0x3F80;  // bf16 1.0

  for (int kt = 0; kt < 32; ++kt) {
    __syncthreads();
    if (kt < 31) stage((kt + 1) & 1, kt + 1);
    const u16* vs = Vs[kt & 1];
#pragma unroll
    for (int kk = 0; kk < 2; ++kk) {
      int jt = kt * 2 + kk;
      s8v vf[NF];
#pragma unroll
      for (int nf = 0; nf < NF; ++nf) {
        int c = wc * (NF * 16) + nf * 16 + lr;    // (c&7) == (lr&7)
        int chn = (kk * 4 + lq) ^ (lr & 7);       // same XOR on read
        vf[nf] = *(const s8v*)&vs[c * 64 + chn * 8];
      }
      float4 pa4 = *(const float4*)&e2s[jt * 32 + lq * 8];
      float4 pb4 = *(const float4*)&e2s[jt * 32 + lq * 8 + 4];
      float4 na4 = *(const float4*)&e2n[jt * 32 + lq * 8];
      float4 nb4 = *(const float4*)&e2n[jt * 32 + lq * 8 + 4];
      float ps[8] = {pa4.x, pa4.y, pa4.z, pa4.w, pb4.x, pb4.y, pb4.z, pb4.w};
      float ns[8] = {na4.x, na4.y, na4.z, na4.w, nb4.x, nb4.y, nb4.z, nb4.w};
      unsigned awl = adjs[(wrs * 16 + lr) * 65 + jt] >> (lq * 8);
      union { s8v v; unsigned u[4]; } pk;
#pragma unroll
      for (int ep = 0; ep < 4; ++ep) {
        fp2 ep2 = {ps[2 * ep], ps[2 * ep + 1]};
        fp2 en2 = {ns[2 * ep], ns[2 * ep + 1]};
        fp2 pm = __builtin_elementwise_max(Ap * ep2, Bp * en2);
        float p0 = ((awl >> (2 * ep)) & 1u) ? pm[0] : 0.f;
        float p1 = ((awl >> (2 * ep + 1)) & 1u) ? pm[1] : 0.f;
        asm("v_cvt_pk_bf16_f32 %0, %1, %2"
            : "=v"(pk.u[ep]) : "v"(p0), "v"(p1));
      }
      s8v pa = pk.v;
      accs = mfma16(pa, ones, accs);  // row sums in C/D layout
#pragma unroll
      for (int nf = 0; nf < NF; ++nf)
        acc[nf] = mfma16(pa, vf[nf], acc[nf]);
    }
  }
  // accs[r] = full row sum for output row lq*4+r (all k covered by MFMA)
  f4v i4;
#pragma unroll
  for (int r = 0; r < 4; ++r) i4[r] = 1.f / fmaxf(accs[r], 1e-30f);
  int rowb = i0 + wrs * 16 + lq * 4;
  if constexpr (ELU) {
#pragma unroll
    for (int nf = 0; nf < NF; ++nf) {
      int col = col0 + wc * (NF * 16) + nf * 16 + lr;
#pragma unroll
      for (int r = 0; r < 4; ++r) {
        float v = acc[nf][r] * i4[r];
        v = v > 0.f ? v : exp2fast(v * L2E) - 1.f;
        ((u16*)outp)[(size_t)(b * N + rowb + r) * CT + col] = f2bf(v);
      }
    }
  } else {
    float mk[4];
#pragma unroll
    for (int r = 0; r < 4; ++r) mk[r] = mask[b * N + rowb + r];
#pragma unroll
    for (int nf = 0; nf < NF; ++nf) {
      int col = col0 + wc * (NF * 16) + nf * 16 + lr;
      float cs = 0.f;
#pragma unroll
      for (int r = 0; r < 4; ++r) {
        float vm = acc[nf][r] * i4[r] * mk[r];
        ((float*)outp)[(size_t)(b * N + rowb + r) * CT + col] = vm;
        cs += vm;
      }
      // fused pool1: column partial sums (sum over this wave's 16 rows)
      cs += __shfl_xor(cs, 16);
      cs += __shfl_xor(cs, 32);
      if (l < 16) atomicAdd(&pool[b * 256 + col], cs);
    }
  }
}

// ---------------- pooling epilogue: den from mask + final GEMM --------------
__global__ __launch_bounds__(256) void pool2(const float* __restrict__ pool,
                                             const float* __restrict__ mask,
                                             const float* __restrict__ Wp,
                                             const float* __restrict__ bp,
                                             float* __restrict__ out) {
  int b = blockIdx.x, f = threadIdx.x;
  __shared__ float pv[256];
  __shared__ float ds[256];
  float m = 0.f;
#pragma unroll
  for (int k = 0; k < 8; ++k) m += mask[b * 2048 + f + k * 256];
  ds[f] = m;
  __syncthreads();
  for (int s = 128; s > 0; s >>= 1) {
    if (f < s) ds[f] += ds[f + s];
    __syncthreads();
  }
  float inv = 1.f / (ds[0] + 1e-10f);
  pv[f] = pool[b * 256 + f] * inv;
  __syncthreads();
  float acc = bp[f];
  for (int c = 0; c < 256; ++c) acc = fmaf(pv[c], Wp[c * 256 + f], acc);
  out[b * 256 + f] = fmaxf(acc, 0.f);
}

// ---------------- launcher ----------------
extern "C" void kernel_launch(void* const* d_in, const int* in_sizes, int n_in,
                              void* d_out, int out_size, void* d_ws,
                              size_t ws_size, hipStream_t stream) {
  (void)in_sizes; (void)n_in; (void)out_size; (void)ws_size;
  const float* x = (const float*)d_in[0];
  const int* adj = (const int*)d_in[1];
  const float* mask = (const float*)d_in[2];
  const float* Whds = (const float*)d_in[3];
  const float* ahds = (const float*)d_in[4];
  const float* Wout = (const float*)d_in[5];
  const float* aout = (const float*)d_in[6];
  const float* Wpool = (const float*)d_in[7];
  const float* bpool = (const float*)d_in[8];
  float* out = (float*)d_out;

  char* ws = (char*)d_ws;
  size_t off = 0;
  auto take = [&](size_t n) {
    char* p = ws + off;
    off += (n + 255) & ~(size_t)255;
    return p;
  };
  u16* xb = (u16*)take(8192ull * 512 * 2);
  u16* Wta = (u16*)take(512ull * 512 * 2);
  u16* Wto = (u16*)take(256ull * 512 * 2);
  unsigned* adjw = (unsigned*)take(4ull * 2048 * 64 * 4);
  u16* Wht = (u16*)take(4ull * 512 * 2048 * 2);
  float* f1a = (float*)take(4ull * 4 * 2048 * 4);
  float* f2a = (float*)take(4ull * 4 * 2048 * 4);
  u16* xcat = (u16*)take(8192ull * 512 * 2);
  u16* Wh2t = (u16*)take(4ull * 256 * 2048 * 2);
  float* f1b = (float*)take(4ull * 2048 * 4);
  float* f2b = (float*)take(4ull * 2048 * 4);
  float* f2ma = (float*)take(16 * 4);
  float* f2mb = (float*)take(4 * 4);
  float* pool = (float*)take(1024 * 4);

  prep_all<<<3584, 256, 0, stream>>>(x, xb, Whds, Wta, Wout, Wto);
  prep_adj<<<65536, 256, 0, stream>>>(adj, adjw);
  gemm_bf16<<<dim3(128, 8), 256, 0, stream>>>(xb, Wta, Wht, 512);
  fkern<<<dim3(32, 4, 4), 256, 0, stream>>>(Wht, ahds, f1a, f2a, 512, 128);
  fmax_kern<<<16, 256, 0, stream>>>(f2a, f2ma, nullptr);
  attn_kernel<512, 4, 4, true><<<512, 256, 0, stream>>>(
      Wht, f1a, f2a, f2ma, adjw, nullptr, xcat, nullptr);
  gemm_bf16<<<dim3(128, 4), 256, 0, stream>>>(xcat, Wto, Wh2t, 256);
  fkern<<<dim3(32, 4, 1), 256, 0, stream>>>(Wh2t, aout, f1b, f2b, 256, 256);
  fmax_kern<<<4, 256, 0, stream>>>(f2b, f2mb, pool);
  attn_kernel<256, 4, 2, false><<<512, 256, 0, stream>>>(
      Wh2t, f1b, f2b, f2mb, adjw, mask, out + 1024, pool);
  pool2<<<4, 256, 0, stream>>>(pool, mask, Wpool, bpool, out);
}